// Round 5
// baseline (200.364 us; speedup 1.0000x reference)
//
#include <hip/hip_runtime.h>
#include <hip/hip_bf16.h>
#include <stdint.h>
#include <stddef.h>

typedef __bf16 bf16;
typedef __bf16 bf16x8 __attribute__((ext_vector_type(8)));
typedef float f32x4 __attribute__((ext_vector_type(4)));
typedef float f32x16 __attribute__((ext_vector_type(16)));

// ---------------- helpers ----------------

__device__ __forceinline__ void gload16(const void* g, void* lds) {
  __builtin_amdgcn_global_load_lds(
      (const __attribute__((address_space(1))) unsigned int*)(uintptr_t)g,
      (__attribute__((address_space(3))) unsigned int*)(unsigned int)(uintptr_t)lds,
      16, 0, 0);
}

// rows are 64 bf16 = 128B. slot = 16B chunk index [0,8). XOR-swizzled.
__device__ __forceinline__ bf16x8 lds_read8(const bf16* base, int row, int slot) {
  const char* p = (const char*)base + row * 128 + ((slot ^ (row & 7)) << 4);
  return *(const bf16x8*)p;
}

// ---------------- kernel 1: embedded fp32 -> bf16 ----------------

__global__ void k_cvt_embed(const float* __restrict__ src, bf16* __restrict__ dst) {
  int i = blockIdx.x * blockDim.x + threadIdx.x;
  const float4* s4 = (const float4*)src;
  float4 a = s4[2 * i], b = s4[2 * i + 1];
  bf16x8 v;
  v[0] = (bf16)a.x; v[1] = (bf16)a.y; v[2] = (bf16)a.z; v[3] = (bf16)a.w;
  v[4] = (bf16)b.x; v[5] = (bf16)b.y; v[6] = (bf16)b.z; v[7] = (bf16)b.w;
  ((bf16x8*)dst)[i] = v;
}

// ---------------- kernel 2: weights -> bf16 (QKV transposed to B^T) --------

__global__ void k_cvt_w(const float* __restrict__ Wq, const float* __restrict__ Wk,
                        const float* __restrict__ Wv, const float* __restrict__ Wo,
                        bf16* __restrict__ WT, bf16* __restrict__ WoB) {
  int i = blockIdx.x * blockDim.x + threadIdx.x;
  if (i < 16 * 192 * 1024) {
    int h = i / (192 * 1024);
    int rem = i - h * (192 * 1024);
    int r = rem >> 10;
    int d = rem & 1023;
    const float* W = (r < 64) ? Wq : (r < 128 ? Wk : Wv);
    int e = r & 63;
    WT[i] = (bf16)W[h * 65536 + d * 64 + e];
  } else {
    int j = i - 16 * 192 * 1024;
    WoB[j] = (bf16)Wo[j];
  }
}

// ---------------- kernel 3: QKV projection GEMM ----------------
// Q columns are pre-scaled by 1/sqrt(64)*log2(e) (softmax scale folded in).

__launch_bounds__(256, 2)
__global__ void k_qkv(const bf16* __restrict__ E, const bf16* __restrict__ WT,
                      bf16* __restrict__ Qo, bf16* __restrict__ Ko, bf16* __restrict__ Vo) {
  __shared__ __align__(16) bf16 As[128 * 64];
  __shared__ __align__(16) bf16 Bs[192 * 64];
  const int h = blockIdx.y;
  const int m0 = blockIdx.x * 128;
  const int tid = threadIdx.x;
  const int w = tid >> 6, lane = tid & 63;
  const int wm = w >> 1, wn = w & 1;
  const int cl = lane & 15, g4 = lane >> 4;
  const int srow = lane >> 3;
  const int scol = ((lane & 7) ^ (lane >> 3)) << 3;
  const bf16* Wh = WT + (size_t)h * 192 * 1024;
  f32x4 zero = {0.f, 0.f, 0.f, 0.f};
  f32x4 acc[4][6];
#pragma unroll
  for (int m = 0; m < 4; ++m)
#pragma unroll
    for (int n = 0; n < 6; ++n) acc[m][n] = zero;

  for (int kt = 0; kt < 16; ++kt) {
    const int k0 = kt * 64;
    __syncthreads();
#pragma unroll
    for (int c = 0; c < 4; ++c) {
      int cc = w * 4 + c;
      gload16(E + (size_t)(m0 + cc * 8 + srow) * 1024 + k0 + scol, (char*)As + cc * 1024);
    }
#pragma unroll
    for (int c = 0; c < 6; ++c) {
      int cc = w * 6 + c;
      gload16(Wh + (size_t)(cc * 8 + srow) * 1024 + k0 + scol, (char*)Bs + cc * 1024);
    }
    __syncthreads();
#pragma unroll
    for (int kk = 0; kk < 2; ++kk) {
      bf16x8 a[4], b[6];
#pragma unroll
      for (int m = 0; m < 4; ++m) a[m] = lds_read8(As, wm * 64 + m * 16 + cl, kk * 4 + g4);
#pragma unroll
      for (int n = 0; n < 6; ++n) b[n] = lds_read8(Bs, wn * 96 + n * 16 + cl, kk * 4 + g4);
#pragma unroll
      for (int m = 0; m < 4; ++m)
#pragma unroll
        for (int n = 0; n < 6; ++n)
          acc[m][n] = __builtin_amdgcn_mfma_f32_16x16x32_bf16(a[m], b[n], acc[m][n], 0, 0, 0);
    }
  }
#pragma unroll
  for (int n = 0; n < 6; ++n) {
    int ncol = wn * 96 + n * 16 + cl;
    int which = ncol >> 6, e = ncol & 63;
    bf16* dst = which == 0 ? Qo : (which == 1 ? Ko : Vo);
    const float sc = (which == 0) ? 0.18033688f : 1.0f;   // 0.125 * log2(e)
#pragma unroll
    for (int m = 0; m < 4; ++m) {
#pragma unroll
      for (int r = 0; r < 4; ++r) {
        int row = m0 + wm * 64 + m * 16 + g4 * 4 + r;
        int bb = row >> 11, ss = row & 2047;
        dst[(((size_t)(bb * 16 + h) * 2048 + ss) << 6) + e] = (bf16)(acc[m][n][r] * sc);
      }
    }
  }
}

// ---------------- kernel 4: causal flash attention (4-warp, QBLK=128) ------
// 1024 blocks x 256 thr, 4 blocks/CU. bh = b&63, t = b>>6 (0..15),
// qt' = [0,1,2,3, 15,14,13,12, 4,5,6,7, 11,10,9,8][t] -> co-resident quad
// {t,t+4,t+8,t+12} has qt' {a,15-a,b,15-b}: exactly 68 iters per CU.
// Swapped QK^T: S^T = mfma(K,Q) -> lane holds P[q=lane&31][32 keys] in regs.
// Swapped PV:  O^T = mfma(V^T,P).  V^T columns stored permuted by
// phi(key)=swap bits2<->3 -> PV B-fragment is lane-local p[ks*8+j].

__launch_bounds__(256)
__global__ void k_attn(const bf16* __restrict__ Qg, const bf16* __restrict__ Kg,
                       const bf16* __restrict__ Vg, bf16* __restrict__ CTX) {
  __shared__ __align__(16) bf16 KS[2][4096];   // [key][d] 64x64, XOR-swizzled
  __shared__ __align__(16) bf16 VT[2][4096];   // [d][phi(key)] 64x64, XOR-swizzled
  const int b = blockIdx.x;
  const int bh = b & 63;
  const int t16 = b >> 6;                      // 0..15
  const int g = t16 >> 2;
  const int qt = (g == 0) ? t16 : (g == 1) ? 19 - t16 : (g == 2) ? t16 - 4 : 23 - t16;
  const int q0 = qt * 128;
  const int tid = threadIdx.x, w = tid >> 6, lane = tid & 63;
  const int ql = lane & 31, hi = lane >> 5;
  const int q = q0 + 32 * w + ql;
  const int qmin = q0 + 32 * w;
  const int qmax = qmin + 31;
  const bf16* Qb = Qg + (size_t)bh * (2048 * 64);
  const bf16* Kb = Kg + (size_t)bh * (2048 * 64);
  const bf16* Vb = Vg + (size_t)bh * (2048 * 64);
  const int nkv = 2 * qt + 2;

  // Q fragments: qf[ks][j] = Q[q][ks*16 + 8*hi + j]  (pre-scaled in k_qkv)
  bf16x8 qf[4];
#pragma unroll
  for (int ks = 0; ks < 4; ++ks)
    qf[ks] = *(const bf16x8*)(Qb + (size_t)q * 64 + ks * 16 + hi * 8);

  f32x16 o0, o1;
#pragma unroll
  for (int i = 0; i < 16; ++i) { o0[i] = 0.f; o1[i] = 0.f; }
  float mr = -1e30f, ls = 0.f;

  // staging geometry (256 threads): K in 2 passes of 32 rows; V 16 elems/thread
  const int srowK = lane >> 3;                               // within-pass row % 8 block
  const int scolK = ((lane & 7) ^ ((lane >> 3) & 7)) << 3;   // pre-swizzled src col
  const int lanep = (lane & ~12) | ((lane & 4) << 1) | ((lane & 8) >> 1);  // phi(lane)
  int offs[4];
#pragma unroll
  for (int ks = 0; ks < 4; ++ks) offs[ks] = (ks * 32 + hi * 16) ^ ((ql & 7) << 4);

  // prologue: stage tile 0 into buf 0
  {
#pragma unroll
    for (int c = 0; c < 2; ++c)
      gload16(Kb + (size_t)(c * 32 + w * 8 + srowK) * 64 + scolK,
              (char*)KS[0] + c * 4096 + w * 1024);
    bf16x8 v0 = *(const bf16x8*)(Vb + (size_t)lane * 64 + w * 16);
    bf16x8 v1 = *(const bf16x8*)(Vb + (size_t)lane * 64 + w * 16 + 8);
#pragma unroll
    for (int j = 0; j < 8; ++j) {
      *(bf16*)((char*)VT[0] + w * 2048 + j * 128 + ((lanep * 2) ^ (j << 4))) = v0[j];
      *(bf16*)((char*)VT[0] + w * 2048 + (j + 8) * 128 + ((lanep * 2) ^ (j << 4))) = v1[j];
    }
  }

  int cur = 0;
  for (int t = 0; t < nkv; ++t) {
    const int kv0 = t * 64;
    __syncthreads();                              // buf[cur] ready; buf[cur^1] free
    bf16x8 vn0, vn1;
    const bool more = (t + 1 < nkv);
    if (more) {
      const int kn = kv0 + 64;
      vn0 = *(const bf16x8*)(Vb + (size_t)(kn + lane) * 64 + w * 16);       // issue early
      vn1 = *(const bf16x8*)(Vb + (size_t)(kn + lane) * 64 + w * 16 + 8);
#pragma unroll
      for (int c = 0; c < 2; ++c)
        gload16(Kb + (size_t)(kn + c * 32 + w * 8 + srowK) * 64 + scolK,
                (char*)KS[cur ^ 1] + c * 4096 + w * 1024);
    }
    const bool active = (kv0 <= qmax);
    float p[32];
    if (active) {
      // ---- QK^T ----
      f32x16 s0, s1;
#pragma unroll
      for (int i = 0; i < 16; ++i) { s0[i] = 0.f; s1[i] = 0.f; }
      const char* kbase = (const char*)KS[cur];
      __builtin_amdgcn_s_setprio(1);
#pragma unroll
      for (int ks = 0; ks < 4; ++ks) {
        bf16x8 k0 = *(const bf16x8*)(kbase + ql * 128 + offs[ks]);
        bf16x8 k1 = *(const bf16x8*)(kbase + (32 + ql) * 128 + offs[ks]);
        s0 = __builtin_amdgcn_mfma_f32_32x32x16_bf16(k0, qf[ks], s0, 0, 0, 0);
        s1 = __builtin_amdgcn_mfma_f32_32x32x16_bf16(k1, qf[ks], s1, 0, 0, 0);
      }
      __builtin_amdgcn_s_setprio(0);
      // ---- causal mask (scale pre-folded into Q) ----
#pragma unroll
      for (int r = 0; r < 16; ++r) { p[r] = s0[r]; p[16 + r] = s1[r]; }
      if (kv0 + 63 > qmin) {
#pragma unroll
        for (int kb = 0; kb < 2; ++kb)
#pragma unroll
          for (int r = 0; r < 16; ++r) {
            int key = kv0 + kb * 32 + (r & 3) + 8 * (r >> 2) + 4 * hi;
            if (key > q) p[kb * 16 + r] = -1e30f;
          }
      }
      // ---- online softmax (lane-local row; cross-half via shfl_xor 32) ----
      float t8[8];
#pragma unroll
      for (int i = 0; i < 8; ++i)
        t8[i] = fmaxf(fmaxf(fmaxf(p[i], p[i + 8]), p[i + 16]), p[i + 24]);
      float mA = fmaxf(fmaxf(t8[0], t8[1]), fmaxf(t8[2], t8[3]));
      float mB = fmaxf(fmaxf(t8[4], t8[5]), fmaxf(t8[6], t8[7]));
      float pmax = fmaxf(mA, mB);
      pmax = fmaxf(pmax, __shfl_xor(pmax, 32));
      if (__any(pmax - mr > 8.0f)) {              // defer-max (T13)
        float mnew = fmaxf(mr, pmax);
        float al = exp2f(mr - mnew);
        mr = mnew; ls *= al;
#pragma unroll
        for (int i = 0; i < 16; ++i) { o0[i] *= al; o1[i] *= al; }
      }
#pragma unroll
      for (int i = 0; i < 32; ++i) p[i] = exp2f(p[i] - mr);
      float a8[8];
#pragma unroll
      for (int i = 0; i < 8; ++i) a8[i] = (p[i] + p[i + 8]) + (p[i + 16] + p[i + 24]);
      float rs = (a8[0] + a8[1]) + (a8[2] + a8[3]) + (a8[4] + a8[5]) + (a8[6] + a8[7]);
      rs += __shfl_xor(rs, 32);
      ls += rs;
    }
    // ---- write next V tile (transposed, phi-permuted, swizzled) ----
    if (more) {
#pragma unroll
      for (int j = 0; j < 8; ++j) {
        *(bf16*)((char*)VT[cur ^ 1] + w * 2048 + j * 128 + ((lanep * 2) ^ (j << 4))) = vn0[j];
        *(bf16*)((char*)VT[cur ^ 1] + w * 2048 + (j + 8) * 128 + ((lanep * 2) ^ (j << 4))) = vn1[j];
      }
    }
    if (active) {
      // ---- O^T += V^T P  (P fragment is lane-local: element j = p[ks*8+j]) ----
      const char* vbase = (const char*)VT[cur];
      __builtin_amdgcn_s_setprio(1);
#pragma unroll
      for (int ks = 0; ks < 4; ++ks) {
        bf16x8 pf;
#pragma unroll
        for (int j = 0; j < 8; ++j) pf[j] = (bf16)p[ks * 8 + j];
        bf16x8 v0 = *(const bf16x8*)(vbase + ql * 128 + offs[ks]);
        bf16x8 v1 = *(const bf16x8*)(vbase + (32 + ql) * 128 + offs[ks]);
        o0 = __builtin_amdgcn_mfma_f32_32x32x16_bf16(v0, pf, o0, 0, 0, 0);
        o1 = __builtin_amdgcn_mfma_f32_32x32x16_bf16(v1, pf, o1, 0, 0, 0);
      }
      __builtin_amdgcn_s_setprio(0);
    }
    cur ^= 1;
  }

  // epilogue: normalize, write CTX [b][s][h*64+d] bf16
  const float inv = 1.0f / ls;
  const int bb = bh >> 4, hh = bh & 15;
  bf16* Cp = CTX + ((size_t)(bb * 2048 + q) * 1024) + hh * 64;
#pragma unroll
  for (int r = 0; r < 16; ++r) {
    int d0 = (r & 3) + 8 * (r >> 2) + 4 * hi;
    Cp[d0] = (bf16)(o0[r] * inv);
    Cp[32 + d0] = (bf16)(o1[r] * inv);
  }
}

// ---------------- kernel 5: output projection + bias ----------------

__launch_bounds__(256, 2)
__global__ void k_oproj(const bf16* __restrict__ X, const bf16* __restrict__ Wb,
                        const float* __restrict__ bo, float* __restrict__ out) {
  __shared__ __align__(16) bf16 As[128 * 64];
  __shared__ __align__(16) bf16 Bs[128 * 64];
  const int m0 = blockIdx.x * 128, n0 = blockIdx.y * 128;
  const int tid = threadIdx.x, w = tid >> 6, lane = tid & 63;
  const int wm = w >> 1, wn = w & 1;
  const int cl = lane & 15, g4 = lane >> 4;
  const int srow = lane >> 3;
  const int scol = ((lane & 7) ^ (lane >> 3)) << 3;
  f32x4 zero = {0.f, 0.f, 0.f, 0.f};
  f32x4 acc[4][4];
#pragma unroll
  for (int m = 0; m < 4; ++m)
#pragma unroll
    for (int n = 0; n < 4; ++n) acc[m][n] = zero;

  for (int kt = 0; kt < 16; ++kt) {
    const int k0 = kt * 64;
    __syncthreads();
#pragma unroll
    for (int c = 0; c < 4; ++c) {
      int cc = w * 4 + c;
      gload16(X + (size_t)(m0 + cc * 8 + srow) * 1024 + k0 + scol, (char*)As + cc * 1024);
      gload16(Wb + (size_t)(n0 + cc * 8 + srow) * 1024 + k0 + scol, (char*)Bs + cc * 1024);
    }
    __syncthreads();
#pragma unroll
    for (int kk = 0; kk < 2; ++kk) {
      bf16x8 a[4], b[4];
#pragma unroll
      for (int m = 0; m < 4; ++m) a[m] = lds_read8(As, wm * 64 + m * 16 + cl, kk * 4 + g4);
#pragma unroll
      for (int n = 0; n < 4; ++n) b[n] = lds_read8(Bs, wn * 64 + n * 16 + cl, kk * 4 + g4);
#pragma unroll
      for (int m = 0; m < 4; ++m)
#pragma unroll
        for (int n = 0; n < 4; ++n)
          acc[m][n] = __builtin_amdgcn_mfma_f32_16x16x32_bf16(a[m], b[n], acc[m][n], 0, 0, 0);
    }
  }
#pragma unroll
  for (int n = 0; n < 4; ++n) {
    int col = n0 + wn * 64 + n * 16 + cl;
    float bias = bo[col];
#pragma unroll
    for (int m = 0; m < 4; ++m)
#pragma unroll
      for (int r = 0; r < 4; ++r) {
        int row = m0 + wm * 64 + m * 16 + g4 * 4 + r;
        out[(size_t)row * 1024 + col] = acc[m][n][r] + bias;
      }
  }
}

// ---------------- launch ----------------

extern "C" void kernel_launch(void* const* d_in, const int* in_sizes, int n_in,
                              void* d_out, int out_size, void* d_ws, size_t ws_size,
                              hipStream_t stream) {
  const float* emb = (const float*)d_in[0];
  const float* Wq  = (const float*)d_in[1];
  const float* Wk  = (const float*)d_in[2];
  const float* Wv  = (const float*)d_in[3];
  const float* Wo  = (const float*)d_in[4];
  const float* bo  = (const float*)d_in[5];
  float* out = (float*)d_out;

  const size_t NEED = (size_t)72 << 20;
  if (ws_size < NEED) return;

  char* ws = (char*)d_ws;
  bf16* E   = (bf16*)(ws);
  bf16* WT  = (bf16*)(ws + ((size_t)16 << 20));
  bf16* WoB = (bf16*)(ws + ((size_t)22 << 20));
  bf16* Qw  = (bf16*)(ws + ((size_t)24 << 20));
  bf16* Kw  = (bf16*)(ws + ((size_t)40 << 20));
  bf16* Vw  = (bf16*)(ws + ((size_t)56 << 20));
  bf16* CTX = E;

  k_cvt_embed<<<4096, 256, 0, stream>>>(emb, E);
  k_cvt_w<<<16384, 256, 0, stream>>>(Wq, Wk, Wv, Wo, WT, WoB);
  k_qkv<<<dim3(64, 16), 256, 0, stream>>>(E, WT, Qw, Kw, Vw);
  k_attn<<<1024, 256, 0, stream>>>(Qw, Kw, Vw, CTX);
  k_oproj<<<dim3(64, 8), 256, 0, stream>>>(CTX, WoB, bo, out);
}

// Round 6
// 195.942 us; speedup vs baseline: 1.0226x; 1.0226x over previous
//
#include <hip/hip_runtime.h>
#include <hip/hip_bf16.h>
#include <stdint.h>
#include <stddef.h>

typedef __bf16 bf16;
typedef __bf16 bf16x4 __attribute__((ext_vector_type(4)));
typedef __bf16 bf16x8 __attribute__((ext_vector_type(8)));
typedef float f32x4 __attribute__((ext_vector_type(4)));
typedef float f32x16 __attribute__((ext_vector_type(16)));

// ---------------- helpers ----------------

__device__ __forceinline__ void gload16(const void* g, void* lds) {
  __builtin_amdgcn_global_load_lds(
      (const __attribute__((address_space(1))) unsigned int*)(uintptr_t)g,
      (__attribute__((address_space(3))) unsigned int*)(unsigned int)(uintptr_t)lds,
      16, 0, 0);
}

// rows are 64 bf16 = 128B. slot = 16B chunk index [0,8). XOR-swizzled.
__device__ __forceinline__ bf16x8 lds_read8(const bf16* base, int row, int slot) {
  const char* p = (const char*)base + row * 128 + ((slot ^ (row & 7)) << 4);
  return *(const bf16x8*)p;
}

// ---------------- kernel 1: embedded fp32 -> bf16 ----------------

__global__ void k_cvt_embed(const float* __restrict__ src, bf16* __restrict__ dst) {
  int i = blockIdx.x * blockDim.x + threadIdx.x;
  const float4* s4 = (const float4*)src;
  float4 a = s4[2 * i], b = s4[2 * i + 1];
  bf16x8 v;
  v[0] = (bf16)a.x; v[1] = (bf16)a.y; v[2] = (bf16)a.z; v[3] = (bf16)a.w;
  v[4] = (bf16)b.x; v[5] = (bf16)b.y; v[6] = (bf16)b.z; v[7] = (bf16)b.w;
  ((bf16x8*)dst)[i] = v;
}

// ---------------- kernel 2: weights -> bf16 (QKV transposed to B^T) --------

__global__ void k_cvt_w(const float* __restrict__ Wq, const float* __restrict__ Wk,
                        const float* __restrict__ Wv, const float* __restrict__ Wo,
                        bf16* __restrict__ WT, bf16* __restrict__ WoB) {
  int i = blockIdx.x * blockDim.x + threadIdx.x;
  if (i < 16 * 192 * 1024) {
    int h = i / (192 * 1024);
    int rem = i - h * (192 * 1024);
    int r = rem >> 10;
    int d = rem & 1023;
    const float* W = (r < 64) ? Wq : (r < 128 ? Wk : Wv);
    int e = r & 63;
    WT[i] = (bf16)W[h * 65536 + d * 64 + e];
  } else {
    int j = i - 16 * 192 * 1024;
    WoB[j] = (bf16)Wo[j];
  }
}

// ---------------- kernel 3: QKV projection GEMM ----------------
// Q columns are pre-scaled by 1/sqrt(64)*log2(e) (softmax scale folded in).

__launch_bounds__(256, 2)
__global__ void k_qkv(const bf16* __restrict__ E, const bf16* __restrict__ WT,
                      bf16* __restrict__ Qo, bf16* __restrict__ Ko, bf16* __restrict__ Vo) {
  __shared__ __align__(16) bf16 As[128 * 64];
  __shared__ __align__(16) bf16 Bs[192 * 64];
  const int h = blockIdx.y;
  const int m0 = blockIdx.x * 128;
  const int tid = threadIdx.x;
  const int w = tid >> 6, lane = tid & 63;
  const int wm = w >> 1, wn = w & 1;
  const int cl = lane & 15, g4 = lane >> 4;
  const int srow = lane >> 3;
  const int scol = ((lane & 7) ^ (lane >> 3)) << 3;
  const bf16* Wh = WT + (size_t)h * 192 * 1024;
  f32x4 zero = {0.f, 0.f, 0.f, 0.f};
  f32x4 acc[4][6];
#pragma unroll
  for (int m = 0; m < 4; ++m)
#pragma unroll
    for (int n = 0; n < 6; ++n) acc[m][n] = zero;

  for (int kt = 0; kt < 16; ++kt) {
    const int k0 = kt * 64;
    __syncthreads();
#pragma unroll
    for (int c = 0; c < 4; ++c) {
      int cc = w * 4 + c;
      gload16(E + (size_t)(m0 + cc * 8 + srow) * 1024 + k0 + scol, (char*)As + cc * 1024);
    }
#pragma unroll
    for (int c = 0; c < 6; ++c) {
      int cc = w * 6 + c;
      gload16(Wh + (size_t)(cc * 8 + srow) * 1024 + k0 + scol, (char*)Bs + cc * 1024);
    }
    __syncthreads();
#pragma unroll
    for (int kk = 0; kk < 2; ++kk) {
      bf16x8 a[4], b[6];
#pragma unroll
      for (int m = 0; m < 4; ++m) a[m] = lds_read8(As, wm * 64 + m * 16 + cl, kk * 4 + g4);
#pragma unroll
      for (int n = 0; n < 6; ++n) b[n] = lds_read8(Bs, wn * 96 + n * 16 + cl, kk * 4 + g4);
#pragma unroll
      for (int m = 0; m < 4; ++m)
#pragma unroll
        for (int n = 0; n < 6; ++n)
          acc[m][n] = __builtin_amdgcn_mfma_f32_16x16x32_bf16(a[m], b[n], acc[m][n], 0, 0, 0);
    }
  }
#pragma unroll
  for (int n = 0; n < 6; ++n) {
    int ncol = wn * 96 + n * 16 + cl;
    int which = ncol >> 6, e = ncol & 63;
    bf16* dst = which == 0 ? Qo : (which == 1 ? Ko : Vo);
    const float sc = (which == 0) ? 0.18033688f : 1.0f;   // 0.125 * log2(e)
#pragma unroll
    for (int m = 0; m < 4; ++m) {
#pragma unroll
      for (int r = 0; r < 4; ++r) {
        int row = m0 + wm * 64 + m * 16 + g4 * 4 + r;
        int bb = row >> 11, ss = row & 2047;
        dst[(((size_t)(bb * 16 + h) * 2048 + ss) << 6) + e] = (bf16)(acc[m][n][r] * sc);
      }
    }
  }
}

// ---------------- kernel 4: causal flash attention (8-warp, QBLK=256) ------
// MODE 0 (fallback): 512 blocks, piece map qt = t<4 ? t : 11-t (R4 schedule).
// MODE 1 (split-kv): 768 blocks, 12 pieces/head:
//   g<4:  qt=g      unsplit  (kv 0..4qt+4)        -> CTX
//   g4-7: qt=11-g   half 0   (kv 0..2qt+2)        -> partial slot 0
//   g8-11:qt=15-g   half 1   (kv 2qt+2..4qt+4)    -> partial slot 1
// Dispatch triples (g,g+4,g+8) sum to 36 iters on every CU.
// Swapped QK^T: S^T = mfma(K,Q) -> lane holds P[q=lane&31][32 keys] in regs.
// Swapped PV:  O^T = mfma(V^T,P).  V^T columns stored permuted by
// phi(key)=swap bits2<->3 -> PV B-fragment is lane-local p[ks*8+j].

template <int MODE>
__launch_bounds__(512)
__global__ void k_attn(const bf16* __restrict__ Qg, const bf16* __restrict__ Kg,
                       const bf16* __restrict__ Vg, bf16* __restrict__ CTX,
                       bf16* __restrict__ PO, float2* __restrict__ ML) {
  __shared__ __align__(16) bf16 KS[2][4096];   // [key][d] 64x64, XOR-swizzled
  __shared__ __align__(16) bf16 VT[2][4096];   // [d][phi(key)] 64x64, XOR-swizzled
  const int b = blockIdx.x;
  const int bh = b & 63;
  const int g = b >> 6;
  int qt, kvA, slot;
  if (MODE == 0) {
    qt = (g < 4) ? g : 11 - g; kvA = 0; slot = -1;
  } else {
    if (g < 4)      { qt = g;      kvA = 0;          slot = -1; }
    else if (g < 8) { qt = 11 - g; kvA = 0;          slot = 0; }
    else            { qt = 15 - g; kvA = 2 * qt + 2; slot = 1; }
  }
  const int kvB = (slot == 0) ? (2 * qt + 2) : (4 * qt + 4);
  const int q0 = qt * 256;
  const int tid = threadIdx.x, w = tid >> 6, lane = tid & 63;
  const int ql = lane & 31, hi = lane >> 5;
  const int q = q0 + 32 * w + ql;
  const int qmin = q0 + 32 * w;
  const int qmax = qmin + 31;
  const bf16* Qb = Qg + (size_t)bh * (2048 * 64);
  const bf16* Kb = Kg + (size_t)bh * (2048 * 64);
  const bf16* Vb = Vg + (size_t)bh * (2048 * 64);

  // Q fragments: qf[ks][j] = Q[q][ks*16 + 8*hi + j]  (pre-scaled in k_qkv)
  bf16x8 qf[4];
#pragma unroll
  for (int ks = 0; ks < 4; ++ks)
    qf[ks] = *(const bf16x8*)(Qb + (size_t)q * 64 + ks * 16 + hi * 8);

  f32x16 o0, o1;
#pragma unroll
  for (int i = 0; i < 16; ++i) { o0[i] = 0.f; o1[i] = 0.f; }
  float mr = -1e30f, ls = 0.f;

  // staging geometry
  const int srowK = w * 8 + (lane >> 3);
  const int scolK = ((lane & 7) ^ ((lane >> 3) & 7)) << 3;   // pre-swizzled src col
  const int lanep = (lane & ~12) | ((lane & 4) << 1) | ((lane & 8) >> 1);  // phi(lane)
  int offs[4];
#pragma unroll
  for (int ks = 0; ks < 4; ++ks) offs[ks] = (ks * 32 + hi * 16) ^ ((ql & 7) << 4);

  // prologue: stage tile kvA into buf 0
  {
    gload16(Kb + (size_t)(kvA * 64 + srowK) * 64 + scolK, (char*)KS[0] + w * 1024);
    bf16x8 v = *(const bf16x8*)(Vb + (size_t)(kvA * 64 + lane) * 64 + w * 8);
#pragma unroll
    for (int j = 0; j < 8; ++j)
      *(bf16*)((char*)VT[0] + w * 1024 + j * 128 + ((lanep * 2) ^ (j << 4))) = v[j];
  }

  int cur = 0;
  for (int t = kvA; t < kvB; ++t) {
    const int kv0 = t * 64;
    __syncthreads();                              // buf[cur] ready; buf[cur^1] free
    bf16x8 vnext;
    const bool more = (t + 1 < kvB);
    if (more) {
      const int kn = kv0 + 64;
      vnext = *(const bf16x8*)(Vb + (size_t)(kn + lane) * 64 + w * 8);   // issue early
      gload16(Kb + (size_t)(kn + srowK) * 64 + scolK, (char*)KS[cur ^ 1] + w * 1024);
    }
    const bool active = (kv0 <= qmax);
    float p[32];
    if (active) {
      // ---- QK^T ----
      f32x16 s0, s1;
#pragma unroll
      for (int i = 0; i < 16; ++i) { s0[i] = 0.f; s1[i] = 0.f; }
      const char* kbase = (const char*)KS[cur];
      __builtin_amdgcn_s_setprio(1);
#pragma unroll
      for (int ks = 0; ks < 4; ++ks) {
        bf16x8 k0 = *(const bf16x8*)(kbase + ql * 128 + offs[ks]);
        bf16x8 k1 = *(const bf16x8*)(kbase + (32 + ql) * 128 + offs[ks]);
        s0 = __builtin_amdgcn_mfma_f32_32x32x16_bf16(k0, qf[ks], s0, 0, 0, 0);
        s1 = __builtin_amdgcn_mfma_f32_32x32x16_bf16(k1, qf[ks], s1, 0, 0, 0);
      }
      __builtin_amdgcn_s_setprio(0);
      // ---- causal mask (scale pre-folded into Q) ----
#pragma unroll
      for (int r = 0; r < 16; ++r) { p[r] = s0[r]; p[16 + r] = s1[r]; }
      if (kv0 + 63 > qmin) {
#pragma unroll
        for (int kb = 0; kb < 2; ++kb)
#pragma unroll
          for (int r = 0; r < 16; ++r) {
            int key = kv0 + kb * 32 + (r & 3) + 8 * (r >> 2) + 4 * hi;
            if (key > q) p[kb * 16 + r] = -1e30f;
          }
      }
      // ---- online softmax (lane-local row; cross-half via shfl_xor 32) ----
      float t8[8];
#pragma unroll
      for (int i = 0; i < 8; ++i)
        t8[i] = fmaxf(fmaxf(fmaxf(p[i], p[i + 8]), p[i + 16]), p[i + 24]);
      float mA = fmaxf(fmaxf(t8[0], t8[1]), fmaxf(t8[2], t8[3]));
      float mB = fmaxf(fmaxf(t8[4], t8[5]), fmaxf(t8[6], t8[7]));
      float pmax = fmaxf(mA, mB);
      pmax = fmaxf(pmax, __shfl_xor(pmax, 32));
      if (__any(pmax - mr > 8.0f)) {              // defer-max (T13)
        float mnew = fmaxf(mr, pmax);
        float al = exp2f(mr - mnew);
        mr = mnew; ls *= al;
#pragma unroll
        for (int i = 0; i < 16; ++i) { o0[i] *= al; o1[i] *= al; }
      }
#pragma unroll
      for (int i = 0; i < 32; ++i) p[i] = exp2f(p[i] - mr);
      float a8[8];
#pragma unroll
      for (int i = 0; i < 8; ++i) a8[i] = (p[i] + p[i + 8]) + (p[i + 16] + p[i + 24]);
      float rs = (a8[0] + a8[1]) + (a8[2] + a8[3]) + (a8[4] + a8[5]) + (a8[6] + a8[7]);
      rs += __shfl_xor(rs, 32);
      ls += rs;
    }
    // ---- write next V tile (transposed, phi-permuted, swizzled) ----
    if (more) {
#pragma unroll
      for (int j = 0; j < 8; ++j)
        *(bf16*)((char*)VT[cur ^ 1] + w * 1024 + j * 128 + ((lanep * 2) ^ (j << 4))) = vnext[j];
    }
    if (active) {
      // ---- O^T += V^T P  (P fragment is lane-local: element j = p[ks*8+j]) ----
      const char* vbase = (const char*)VT[cur];
      __builtin_amdgcn_s_setprio(1);
#pragma unroll
      for (int ks = 0; ks < 4; ++ks) {
        bf16x8 pf;
#pragma unroll
        for (int j = 0; j < 8; ++j) pf[j] = (bf16)p[ks * 8 + j];
        bf16x8 v0 = *(const bf16x8*)(vbase + ql * 128 + offs[ks]);
        bf16x8 v1 = *(const bf16x8*)(vbase + (32 + ql) * 128 + offs[ks]);
        o0 = __builtin_amdgcn_mfma_f32_32x32x16_bf16(v0, pf, o0, 0, 0, 0);
        o1 = __builtin_amdgcn_mfma_f32_32x32x16_bf16(v1, pf, o1, 0, 0, 0);
      }
      __builtin_amdgcn_s_setprio(0);
    }
    cur ^= 1;
  }

  if (MODE == 1 && slot >= 0) {
    // epilogue: unnormalized bf16 partial + (m, l) per row
    const int tix = (qt - 4) * 64 + bh;
    const int rloc = 32 * w + ql;
    bf16* Pp = PO + (((size_t)slot * 256 + tix) * 256 + rloc) * 64;
#pragma unroll
    for (int r = 0; r < 16; ++r) {
      int d0 = (r & 3) + 8 * (r >> 2) + 4 * hi;
      Pp[d0] = (bf16)o0[r];
      Pp[32 + d0] = (bf16)o1[r];
    }
    if (hi == 0) {
      float2 ml; ml.x = mr; ml.y = ls;
      ML[(tix * 2 + slot) * 256 + rloc] = ml;
    }
  } else {
    // epilogue: normalize, write CTX [b][s][h*64+d] bf16
    const float inv = 1.0f / ls;
    const int bb = bh >> 4, hh = bh & 15;
    bf16* Cp = CTX + ((size_t)(bb * 2048 + q) * 1024) + hh * 64;
#pragma unroll
    for (int r = 0; r < 16; ++r) {
      int d0 = (r & 3) + 8 * (r >> 2) + 4 * hi;
      Cp[d0] = (bf16)(o0[r] * inv);
      Cp[32 + d0] = (bf16)(o1[r] * inv);
    }
  }
}

// ---------------- kernel 4b: combine split-kv partials ----------------
// one block per (qt 4..7, bh) tile; merges 2 partials -> CTX

__launch_bounds__(512)
__global__ void k_combine(const bf16* __restrict__ PO, const float2* __restrict__ ML,
                          bf16* __restrict__ CTX) {
  __shared__ float2 AW[256];                    // per-row (a0, a1)
  const int tix = blockIdx.x;
  const int qt = 4 + (tix >> 6);
  const int bh = tix & 63;
  const int q0 = qt * 256;
  const int bb = bh >> 4, hh = bh & 15;
  const int tid = threadIdx.x;
  if (tid < 256) {
    float2 ml0 = ML[(tix * 2 + 0) * 256 + tid];
    float2 ml1 = ML[(tix * 2 + 1) * 256 + tid];
    float M = fmaxf(ml0.x, ml1.x);
    float w0 = exp2f(ml0.x - M), w1 = exp2f(ml1.x - M);
    float inv = 1.0f / (w0 * ml0.y + w1 * ml1.y);
    float2 aw; aw.x = w0 * inv; aw.y = w1 * inv;
    AW[tid] = aw;
  }
  __syncthreads();
  const bf16* P0 = PO + ((size_t)tix * 256) * 64;
  const bf16* P1 = PO + (((size_t)256 + tix) * 256) * 64;
#pragma unroll
  for (int k = 0; k < 8; ++k) {
    int iq = tid + k * 512;                     // quad index over 256x64
    int row = iq >> 4, d4 = (iq & 15) << 2;
    float2 aw = AW[row];
    bf16x4 a = *(const bf16x4*)(P0 + row * 64 + d4);
    bf16x4 c = *(const bf16x4*)(P1 + row * 64 + d4);
    bf16x4 o;
#pragma unroll
    for (int j = 0; j < 4; ++j)
      o[j] = (bf16)(aw.x * (float)a[j] + aw.y * (float)c[j]);
    *(bf16x4*)(CTX + ((size_t)(bb * 2048 + q0 + row) * 1024) + hh * 64 + d4) = o;
  }
}

// ---------------- kernel 5: output projection + bias ----------------

__launch_bounds__(256, 2)
__global__ void k_oproj(const bf16* __restrict__ X, const bf16* __restrict__ Wb,
                        const float* __restrict__ bo, float* __restrict__ out) {
  __shared__ __align__(16) bf16 As[128 * 64];
  __shared__ __align__(16) bf16 Bs[128 * 64];
  const int m0 = blockIdx.x * 128, n0 = blockIdx.y * 128;
  const int tid = threadIdx.x, w = tid >> 6, lane = tid & 63;
  const int wm = w >> 1, wn = w & 1;
  const int cl = lane & 15, g4 = lane >> 4;
  const int srow = lane >> 3;
  const int scol = ((lane & 7) ^ (lane >> 3)) << 3;
  f32x4 zero = {0.f, 0.f, 0.f, 0.f};
  f32x4 acc[4][4];
#pragma unroll
  for (int m = 0; m < 4; ++m)
#pragma unroll
    for (int n = 0; n < 4; ++n) acc[m][n] = zero;

  for (int kt = 0; kt < 16; ++kt) {
    const int k0 = kt * 64;
    __syncthreads();
#pragma unroll
    for (int c = 0; c < 4; ++c) {
      int cc = w * 4 + c;
      gload16(X + (size_t)(m0 + cc * 8 + srow) * 1024 + k0 + scol, (char*)As + cc * 1024);
      gload16(Wb + (size_t)(n0 + cc * 8 + srow) * 1024 + k0 + scol, (char*)Bs + cc * 1024);
    }
    __syncthreads();
#pragma unroll
    for (int kk = 0; kk < 2; ++kk) {
      bf16x8 a[4], b[4];
#pragma unroll
      for (int m = 0; m < 4; ++m) a[m] = lds_read8(As, wm * 64 + m * 16 + cl, kk * 4 + g4);
#pragma unroll
      for (int n = 0; n < 4; ++n) b[n] = lds_read8(Bs, wn * 64 + n * 16 + cl, kk * 4 + g4);
#pragma unroll
      for (int m = 0; m < 4; ++m)
#pragma unroll
        for (int n = 0; n < 4; ++n)
          acc[m][n] = __builtin_amdgcn_mfma_f32_16x16x32_bf16(a[m], b[n], acc[m][n], 0, 0, 0);
    }
  }
#pragma unroll
  for (int n = 0; n < 4; ++n) {
    int col = n0 + wn * 64 + n * 16 + cl;
    float bias = bo[col];
#pragma unroll
    for (int m = 0; m < 4; ++m)
#pragma unroll
      for (int r = 0; r < 4; ++r) {
        int row = m0 + wm * 64 + m * 16 + g4 * 4 + r;
        out[(size_t)row * 1024 + col] = acc[m][n][r] + bias;
      }
  }
}

// ---------------- launch ----------------

extern "C" void kernel_launch(void* const* d_in, const int* in_sizes, int n_in,
                              void* d_out, int out_size, void* d_ws, size_t ws_size,
                              hipStream_t stream) {
  const float* emb = (const float*)d_in[0];
  const float* Wq  = (const float*)d_in[1];
  const float* Wk  = (const float*)d_in[2];
  const float* Wv  = (const float*)d_in[3];
  const float* Wo  = (const float*)d_in[4];
  const float* bo  = (const float*)d_in[5];
  float* out = (float*)d_out;

  const size_t NEED_BASE  = (size_t)72 << 20;
  const size_t NEED_SPLIT = (size_t)90 << 20;
  if (ws_size < NEED_BASE) return;   // loud failure: output stays poisoned

  char* ws = (char*)d_ws;
  bf16* E    = (bf16*)(ws);
  bf16* WT   = (bf16*)(ws + ((size_t)16 << 20));
  bf16* WoB  = (bf16*)(ws + ((size_t)22 << 20));
  bf16* Qw   = (bf16*)(ws + ((size_t)24 << 20));
  bf16* Kw   = (bf16*)(ws + ((size_t)40 << 20));
  bf16* Vw   = (bf16*)(ws + ((size_t)56 << 20));
  bf16* PO   = (bf16*)(ws + ((size_t)72 << 20));   // 16 MiB (2 slots x 8 MiB)
  float2* ML = (float2*)(ws + ((size_t)88 << 20)); // 1 MiB
  bf16* CTX = E;

  k_cvt_embed<<<4096, 256, 0, stream>>>(emb, E);
  k_cvt_w<<<16384, 256, 0, stream>>>(Wq, Wk, Wv, Wo, WT, WoB);
  k_qkv<<<dim3(64, 16), 256, 0, stream>>>(E, WT, Qw, Kw, Vw);
  if (ws_size >= NEED_SPLIT) {
    k_attn<1><<<768, 512, 0, stream>>>(Qw, Kw, Vw, CTX, PO, ML);
    k_combine<<<256, 512, 0, stream>>>(PO, ML, CTX);
  } else {
    k_attn<0><<<512, 512, 0, stream>>>(Qw, Kw, Vw, CTX, PO, ML);
  }
  k_oproj<<<dim3(64, 8), 256, 0, stream>>>(CTX, WoB, bo, out);
}

// Round 7
// 179.936 us; speedup vs baseline: 1.1135x; 1.0890x over previous
//
#include <hip/hip_runtime.h>
#include <hip/hip_bf16.h>
#include <stdint.h>
#include <stddef.h>

typedef __bf16 bf16;
typedef __bf16 bf16x8 __attribute__((ext_vector_type(8)));
typedef float f32x4 __attribute__((ext_vector_type(4)));
typedef float f32x16 __attribute__((ext_vector_type(16)));

// ---------------- helpers ----------------

__device__ __forceinline__ void gload16(const void* g, void* lds) {
  __builtin_amdgcn_global_load_lds(
      (const __attribute__((address_space(1))) unsigned int*)(uintptr_t)g,
      (__attribute__((address_space(3))) unsigned int*)(unsigned int)(uintptr_t)lds,
      16, 0, 0);
}

// rows are 64 bf16 = 128B. slot = 16B chunk index [0,8). XOR-swizzled.
__device__ __forceinline__ bf16x8 lds_read8(const bf16* base, int row, int slot) {
  const char* p = (const char*)base + row * 128 + ((slot ^ (row & 7)) << 4);
  return *(const bf16x8*)p;
}

// ---------------- kernel 1: embedded fp32 -> bf16 ----------------

__global__ void k_cvt_embed(const float* __restrict__ src, bf16* __restrict__ dst) {
  int i = blockIdx.x * blockDim.x + threadIdx.x;
  const float4* s4 = (const float4*)src;
  float4 a = s4[2 * i], b = s4[2 * i + 1];
  bf16x8 v;
  v[0] = (bf16)a.x; v[1] = (bf16)a.y; v[2] = (bf16)a.z; v[3] = (bf16)a.w;
  v[4] = (bf16)b.x; v[5] = (bf16)b.y; v[6] = (bf16)b.z; v[7] = (bf16)b.w;
  ((bf16x8*)dst)[i] = v;
}

// ---------------- kernel 2: weights -> bf16 (QKV transposed to B^T) --------

__global__ void k_cvt_w(const float* __restrict__ Wq, const float* __restrict__ Wk,
                        const float* __restrict__ Wv, const float* __restrict__ Wo,
                        bf16* __restrict__ WT, bf16* __restrict__ WoB) {
  int i = blockIdx.x * blockDim.x + threadIdx.x;
  if (i < 16 * 192 * 1024) {
    int h = i / (192 * 1024);
    int rem = i - h * (192 * 1024);
    int r = rem >> 10;
    int d = rem & 1023;
    const float* W = (r < 64) ? Wq : (r < 128 ? Wk : Wv);
    int e = r & 63;
    WT[i] = (bf16)W[h * 65536 + d * 64 + e];
  } else {
    int j = i - 16 * 192 * 1024;
    WoB[j] = (bf16)Wo[j];
  }
}

// ---------------- kernel 3: QKV projection GEMM ----------------
// Q columns are pre-scaled by 1/sqrt(64)*log2(e) (softmax scale folded in).

__launch_bounds__(256, 2)
__global__ void k_qkv(const bf16* __restrict__ E, const bf16* __restrict__ WT,
                      bf16* __restrict__ Qo, bf16* __restrict__ Ko, bf16* __restrict__ Vo) {
  __shared__ __align__(16) bf16 As[128 * 64];
  __shared__ __align__(16) bf16 Bs[192 * 64];
  const int h = blockIdx.y;
  const int m0 = blockIdx.x * 128;
  const int tid = threadIdx.x;
  const int w = tid >> 6, lane = tid & 63;
  const int wm = w >> 1, wn = w & 1;
  const int cl = lane & 15, g4 = lane >> 4;
  const int srow = lane >> 3;
  const int scol = ((lane & 7) ^ (lane >> 3)) << 3;
  const bf16* Wh = WT + (size_t)h * 192 * 1024;
  f32x4 zero = {0.f, 0.f, 0.f, 0.f};
  f32x4 acc[4][6];
#pragma unroll
  for (int m = 0; m < 4; ++m)
#pragma unroll
    for (int n = 0; n < 6; ++n) acc[m][n] = zero;

  for (int kt = 0; kt < 16; ++kt) {
    const int k0 = kt * 64;
    __syncthreads();
#pragma unroll
    for (int c = 0; c < 4; ++c) {
      int cc = w * 4 + c;
      gload16(E + (size_t)(m0 + cc * 8 + srow) * 1024 + k0 + scol, (char*)As + cc * 1024);
    }
#pragma unroll
    for (int c = 0; c < 6; ++c) {
      int cc = w * 6 + c;
      gload16(Wh + (size_t)(cc * 8 + srow) * 1024 + k0 + scol, (char*)Bs + cc * 1024);
    }
    __syncthreads();
#pragma unroll
    for (int kk = 0; kk < 2; ++kk) {
      bf16x8 a[4], b[6];
#pragma unroll
      for (int m = 0; m < 4; ++m) a[m] = lds_read8(As, wm * 64 + m * 16 + cl, kk * 4 + g4);
#pragma unroll
      for (int n = 0; n < 6; ++n) b[n] = lds_read8(Bs, wn * 96 + n * 16 + cl, kk * 4 + g4);
#pragma unroll
      for (int m = 0; m < 4; ++m)
#pragma unroll
        for (int n = 0; n < 6; ++n)
          acc[m][n] = __builtin_amdgcn_mfma_f32_16x16x32_bf16(a[m], b[n], acc[m][n], 0, 0, 0);
    }
  }
#pragma unroll
  for (int n = 0; n < 6; ++n) {
    int ncol = wn * 96 + n * 16 + cl;
    int which = ncol >> 6, e = ncol & 63;
    bf16* dst = which == 0 ? Qo : (which == 1 ? Ko : Vo);
    const float sc = (which == 0) ? 0.18033688f : 1.0f;   // 0.125 * log2(e)
#pragma unroll
    for (int m = 0; m < 4; ++m) {
#pragma unroll
      for (int r = 0; r < 4; ++r) {
        int row = m0 + wm * 64 + m * 16 + g4 * 4 + r;
        int bb = row >> 11, ss = row & 2047;
        dst[(((size_t)(bb * 16 + h) * 2048 + ss) << 6) + e] = (bf16)(acc[m][n][r] * sc);
      }
    }
  }
}

// ---------------- kernel 4: causal flash attention (8-warp, KVBLK=128) -----
// 512 blocks x 512 thr. bh = b&63, g = b>>6, qt = g<4 ? g : 11-g.
// Per iteration: 128 keys (two 64-key halves, one barrier pair total).
// Swapped QK^T: S^T = mfma(K,Q) -> lane holds P[q=lane&31][32 keys] in regs.
// Swapped PV:  O^T = mfma(V^T,P).  V^T columns stored permuted by
// phi(key)=swap bits2<->3 -> PV B-fragment is lane-local p[ks*8+j].

__launch_bounds__(512)
__global__ void k_attn(const bf16* __restrict__ Qg, const bf16* __restrict__ Kg,
                       const bf16* __restrict__ Vg, bf16* __restrict__ CTX) {
  __shared__ __align__(16) bf16 KS[2][8192];      // [half][key][d], XOR-swizzled
  __shared__ __align__(16) bf16 VT[2][2][4096];   // [half][d][phi(key)], XOR-swizzled
  const int b = blockIdx.x;
  const int bh = b & 63;
  const int g = b >> 6;
  const int qt = (g < 4) ? g : 11 - g;
  const int q0 = qt * 256;
  const int tid = threadIdx.x, w = tid >> 6, lane = tid & 63;
  const int ql = lane & 31, hi = lane >> 5;
  const int q = q0 + 32 * w + ql;
  const int qmin = q0 + 32 * w;
  const int qmax = qmin + 31;
  const bf16* Qb = Qg + (size_t)bh * (2048 * 64);
  const bf16* Kb = Kg + (size_t)bh * (2048 * 64);
  const bf16* Vb = Vg + (size_t)bh * (2048 * 64);
  const int ntk = 2 * qt + 2;                     // 128-key tiles

  // Q fragments: qf[ks][j] = Q[q][ks*16 + 8*hi + j]  (pre-scaled in k_qkv)
  bf16x8 qf[4];
#pragma unroll
  for (int ks = 0; ks < 4; ++ks)
    qf[ks] = *(const bf16x8*)(Qb + (size_t)q * 64 + ks * 16 + hi * 8);

  f32x16 o0, o1;
#pragma unroll
  for (int i = 0; i < 16; ++i) { o0[i] = 0.f; o1[i] = 0.f; }
  float mr = -1e30f, ls = 0.f;

  // staging geometry
  const int srowK = w * 8 + (lane >> 3);
  const int scolK = ((lane & 7) ^ ((lane >> 3) & 7)) << 3;   // pre-swizzled src col
  const int lanep = (lane & ~12) | ((lane & 4) << 1) | ((lane & 8) >> 1);  // phi(lane)
  int offs[4];
#pragma unroll
  for (int ks = 0; ks < 4; ++ks) offs[ks] = (ks * 32 + hi * 16) ^ ((ql & 7) << 4);

  // one 64-key half: QK^T -> online softmax -> PV
  auto do_half = [&](int kv0h, const char* kbase, const char* vbase) {
    float p[32];
    // ---- QK^T ----
    f32x16 s0, s1;
#pragma unroll
    for (int i = 0; i < 16; ++i) { s0[i] = 0.f; s1[i] = 0.f; }
    __builtin_amdgcn_s_setprio(1);
#pragma unroll
    for (int ks = 0; ks < 4; ++ks) {
      bf16x8 k0 = *(const bf16x8*)(kbase + ql * 128 + offs[ks]);
      bf16x8 k1 = *(const bf16x8*)(kbase + (32 + ql) * 128 + offs[ks]);
      s0 = __builtin_amdgcn_mfma_f32_32x32x16_bf16(k0, qf[ks], s0, 0, 0, 0);
      s1 = __builtin_amdgcn_mfma_f32_32x32x16_bf16(k1, qf[ks], s1, 0, 0, 0);
    }
    __builtin_amdgcn_s_setprio(0);
    // ---- causal mask (scale pre-folded into Q) ----
#pragma unroll
    for (int r = 0; r < 16; ++r) { p[r] = s0[r]; p[16 + r] = s1[r]; }
    if (kv0h + 63 > qmin) {
#pragma unroll
      for (int kb = 0; kb < 2; ++kb)
#pragma unroll
        for (int r = 0; r < 16; ++r) {
          int key = kv0h + kb * 32 + (r & 3) + 8 * (r >> 2) + 4 * hi;
          if (key > q) p[kb * 16 + r] = -1e30f;
        }
    }
    // ---- online softmax (lane-local row; cross-half via shfl_xor 32) ----
    float t8[8];
#pragma unroll
    for (int i = 0; i < 8; ++i)
      t8[i] = fmaxf(fmaxf(fmaxf(p[i], p[i + 8]), p[i + 16]), p[i + 24]);
    float mA = fmaxf(fmaxf(t8[0], t8[1]), fmaxf(t8[2], t8[3]));
    float mB = fmaxf(fmaxf(t8[4], t8[5]), fmaxf(t8[6], t8[7]));
    float pmax = fmaxf(mA, mB);
    pmax = fmaxf(pmax, __shfl_xor(pmax, 32));
    if (__any(pmax - mr > 8.0f)) {                // defer-max (T13)
      float mnew = fmaxf(mr, pmax);
      float al = exp2f(mr - mnew);
      mr = mnew; ls *= al;
#pragma unroll
      for (int i = 0; i < 16; ++i) { o0[i] *= al; o1[i] *= al; }
    }
#pragma unroll
    for (int i = 0; i < 32; ++i) p[i] = exp2f(p[i] - mr);
    float a8[8];
#pragma unroll
    for (int i = 0; i < 8; ++i) a8[i] = (p[i] + p[i + 8]) + (p[i + 16] + p[i + 24]);
    float rs = (a8[0] + a8[1]) + (a8[2] + a8[3]) + (a8[4] + a8[5]) + (a8[6] + a8[7]);
    rs += __shfl_xor(rs, 32);
    ls += rs;
    // ---- O^T += V^T P  (P fragment is lane-local: element j = p[ks*8+j]) ----
    __builtin_amdgcn_s_setprio(1);
#pragma unroll
    for (int ks = 0; ks < 4; ++ks) {
      bf16x8 pf;
#pragma unroll
      for (int j = 0; j < 8; ++j) pf[j] = (bf16)p[ks * 8 + j];
      bf16x8 v0 = *(const bf16x8*)(vbase + ql * 128 + offs[ks]);
      bf16x8 v1 = *(const bf16x8*)(vbase + (32 + ql) * 128 + offs[ks]);
      o0 = __builtin_amdgcn_mfma_f32_32x32x16_bf16(v0, pf, o0, 0, 0, 0);
      o1 = __builtin_amdgcn_mfma_f32_32x32x16_bf16(v1, pf, o1, 0, 0, 0);
    }
    __builtin_amdgcn_s_setprio(0);
  };

  // prologue: stage tile 0 (128 keys) into buf 0
  {
    gload16(Kb + (size_t)srowK * 64 + scolK, (char*)KS[0] + w * 1024);
    gload16(Kb + (size_t)(64 + srowK) * 64 + scolK, (char*)KS[0] + 8192 + w * 1024);
    bf16x8 v0 = *(const bf16x8*)(Vb + (size_t)lane * 64 + w * 8);
    bf16x8 v1 = *(const bf16x8*)(Vb + (size_t)(64 + lane) * 64 + w * 8);
#pragma unroll
    for (int j = 0; j < 8; ++j) {
      *(bf16*)((char*)VT[0][0] + w * 1024 + j * 128 + ((lanep * 2) ^ (j << 4))) = v0[j];
      *(bf16*)((char*)VT[0][1] + w * 1024 + j * 128 + ((lanep * 2) ^ (j << 4))) = v1[j];
    }
  }

  int cur = 0;
  for (int t = 0; t < ntk; ++t) {
    const int kv0 = t * 128;
    __syncthreads();                              // buf[cur] ready; buf[cur^1] free
    bf16x8 vn0, vn1;
    const bool more = (t + 1 < ntk);
    if (more) {
      const int kn = kv0 + 128;
      vn0 = *(const bf16x8*)(Vb + (size_t)(kn + lane) * 64 + w * 8);       // issue early
      vn1 = *(const bf16x8*)(Vb + (size_t)(kn + 64 + lane) * 64 + w * 8);
      gload16(Kb + (size_t)(kn + srowK) * 64 + scolK, (char*)KS[cur ^ 1] + w * 1024);
      gload16(Kb + (size_t)(kn + 64 + srowK) * 64 + scolK, (char*)KS[cur ^ 1] + 8192 + w * 1024);
    }
    // ---- half 0 ----
    if (kv0 <= qmax)
      do_half(kv0, (const char*)KS[cur], (const char*)VT[cur][0]);
    // ---- write next V tile (transposed, phi-permuted, swizzled) ----
    if (more) {
#pragma unroll
      for (int j = 0; j < 8; ++j) {
        *(bf16*)((char*)VT[cur ^ 1][0] + w * 1024 + j * 128 + ((lanep * 2) ^ (j << 4))) = vn0[j];
        *(bf16*)((char*)VT[cur ^ 1][1] + w * 1024 + j * 128 + ((lanep * 2) ^ (j << 4))) = vn1[j];
      }
    }
    // ---- half 1 ----
    if (kv0 + 64 <= qmax)
      do_half(kv0 + 64, (const char*)KS[cur] + 8192, (const char*)VT[cur][1]);
    cur ^= 1;
  }

  // epilogue: normalize, write CTX [b][s][h*64+d] bf16
  const float inv = 1.0f / ls;
  const int bb = bh >> 4, hh = bh & 15;
  bf16* Cp = CTX + ((size_t)(bb * 2048 + q) * 1024) + hh * 64;
#pragma unroll
  for (int r = 0; r < 16; ++r) {
    int d0 = (r & 3) + 8 * (r >> 2) + 4 * hi;
    Cp[d0] = (bf16)(o0[r] * inv);
    Cp[32 + d0] = (bf16)(o1[r] * inv);
  }
}

// ---------------- kernel 5: output projection + bias ----------------

__launch_bounds__(256, 2)
__global__ void k_oproj(const bf16* __restrict__ X, const bf16* __restrict__ Wb,
                        const float* __restrict__ bo, float* __restrict__ out) {
  __shared__ __align__(16) bf16 As[128 * 64];
  __shared__ __align__(16) bf16 Bs[128 * 64];
  const int m0 = blockIdx.x * 128, n0 = blockIdx.y * 128;
  const int tid = threadIdx.x, w = tid >> 6, lane = tid & 63;
  const int wm = w >> 1, wn = w & 1;
  const int cl = lane & 15, g4 = lane >> 4;
  const int srow = lane >> 3;
  const int scol = ((lane & 7) ^ (lane >> 3)) << 3;
  f32x4 zero = {0.f, 0.f, 0.f, 0.f};
  f32x4 acc[4][4];
#pragma unroll
  for (int m = 0; m < 4; ++m)
#pragma unroll
    for (int n = 0; n < 4; ++n) acc[m][n] = zero;

  for (int kt = 0; kt < 16; ++kt) {
    const int k0 = kt * 64;
    __syncthreads();
#pragma unroll
    for (int c = 0; c < 4; ++c) {
      int cc = w * 4 + c;
      gload16(X + (size_t)(m0 + cc * 8 + srow) * 1024 + k0 + scol, (char*)As + cc * 1024);
      gload16(Wb + (size_t)(n0 + cc * 8 + srow) * 1024 + k0 + scol, (char*)Bs + cc * 1024);
    }
    __syncthreads();
#pragma unroll
    for (int kk = 0; kk < 2; ++kk) {
      bf16x8 a[4], b[4];
#pragma unroll
      for (int m = 0; m < 4; ++m) a[m] = lds_read8(As, wm * 64 + m * 16 + cl, kk * 4 + g4);
#pragma unroll
      for (int n = 0; n < 4; ++n) b[n] = lds_read8(Bs, wn * 64 + n * 16 + cl, kk * 4 + g4);
#pragma unroll
      for (int m = 0; m < 4; ++m)
#pragma unroll
        for (int n = 0; n < 4; ++n)
          acc[m][n] = __builtin_amdgcn_mfma_f32_16x16x32_bf16(a[m], b[n], acc[m][n], 0, 0, 0);
    }
  }
#pragma unroll
  for (int n = 0; n < 4; ++n) {
    int col = n0 + wn * 64 + n * 16 + cl;
    float bias = bo[col];
#pragma unroll
    for (int m = 0; m < 4; ++m)
#pragma unroll
      for (int r = 0; r < 4; ++r) {
        int row = m0 + wm * 64 + m * 16 + g4 * 4 + r;
        out[(size_t)row * 1024 + col] = acc[m][n][r] + bias;
      }
  }
}

// ---------------- launch ----------------

extern "C" void kernel_launch(void* const* d_in, const int* in_sizes, int n_in,
                              void* d_out, int out_size, void* d_ws, size_t ws_size,
                              hipStream_t stream) {
  const float* emb = (const float*)d_in[0];
  const float* Wq  = (const float*)d_in[1];
  const float* Wk  = (const float*)d_in[2];
  const float* Wv  = (const float*)d_in[3];
  const float* Wo  = (const float*)d_in[4];
  const float* bo  = (const float*)d_in[5];
  float* out = (float*)d_out;

  const size_t NEED = (size_t)72 << 20;
  if (ws_size < NEED) return;   // loud failure: output stays poisoned

  char* ws = (char*)d_ws;
  bf16* E   = (bf16*)(ws);
  bf16* WT  = (bf16*)(ws + ((size_t)16 << 20));
  bf16* WoB = (bf16*)(ws + ((size_t)22 << 20));
  bf16* Qw  = (bf16*)(ws + ((size_t)24 << 20));
  bf16* Kw  = (bf16*)(ws + ((size_t)40 << 20));
  bf16* Vw  = (bf16*)(ws + ((size_t)56 << 20));
  bf16* CTX = E;

  k_cvt_embed<<<4096, 256, 0, stream>>>(emb, E);
  k_cvt_w<<<16384, 256, 0, stream>>>(Wq, Wk, Wv, Wo, WT, WoB);
  k_qkv<<<dim3(64, 16), 256, 0, stream>>>(E, WT, Qw, Kw, Vw);
  k_attn<<<512, 512, 0, stream>>>(Qw, Kw, Vw, CTX);
  k_oproj<<<dim3(64, 8), 256, 0, stream>>>(CTX, WoB, bo, out);
}